// Round 8
// baseline (216.451 us; speedup 1.0000x reference)
//
#include <hip/hip_runtime.h>

typedef unsigned short u16;
typedef unsigned int u32;
typedef __bf16 bf16x8_t __attribute__((ext_vector_type(8)));
typedef float f32x4 __attribute__((ext_vector_type(4)));
typedef float f32x2 __attribute__((ext_vector_type(2)));
typedef u32 u32x4 __attribute__((ext_vector_type(4)));
typedef u16 u16x8 __attribute__((ext_vector_type(8)));

__device__ __forceinline__ float b2f(u16 u) {
  u32 x = ((u32)u) << 16; float f; __builtin_memcpy(&f, &x, 4); return f;
}
__device__ __forceinline__ u16 f2b(float f) {
  u32 x; __builtin_memcpy(&x, &f, 4);
  return (u16)((x + 0x8000u) >> 16);
}
// Unpack 2 packed bf16 (one u32) -> float2 in (even, odd) element order.
__device__ __forceinline__ f32x2 up2(u32 w) {
  u32 lo = w << 16, hi = w & 0xffff0000u;
  float a, b; __builtin_memcpy(&a, &lo, 4); __builtin_memcpy(&b, &hi, 4);
  f32x2 r; r[0] = a; r[1] = b; return r;
}

// Load 8 contiguous logical elements at element-offset `off` as bf16,
// from either a bf16 or an f32 array (flag wave-uniform).
__device__ __forceinline__ u16x8 ld8(const void* p, size_t off, int f32) {
  if (!f32) return *(const u16x8*)((const u16*)p + off);
  const u32* u = (const u32*)p + off;
  u32x4 a = *(const u32x4*)u;
  u32x4 b = *(const u32x4*)(u + 4);
  u16x8 r;
#pragma unroll
  for (int e = 0; e < 4; ++e) r[e] = (u16)((a[e] + 0x8000u) >> 16);
#pragma unroll
  for (int e = 0; e < 4; ++e) r[4 + e] = (u16)((b[e] + 0x8000u) >> 16);
  return r;
}

// Async global->LDS, 16 B per lane (wave-uniform LDS base, m97/m104).
#if __has_builtin(__builtin_amdgcn_global_load_lds)
__device__ __forceinline__ void gl_lds16(const u16* g, u16* l, int lane) {
  (void)lane;
  __builtin_amdgcn_global_load_lds(
      (const __attribute__((address_space(1))) void*)g,
      (__attribute__((address_space(3))) void*)l, 16, 0, 0);
}
#else
__device__ __forceinline__ void gl_lds16(const u16* g, u16* l, int lane) {
  *(u16x8*)(l + lane * 8) = *(const u16x8*)g;
}
#endif

// ---------------------------------------------------------------------------
// Inline wave-level input-dtype detection (all waves compute identical flags).
// ---------------------------------------------------------------------------
__device__ __forceinline__ int det_f32(const u32* qraw, int lane) {
  int c = 0;
#pragma unroll
  for (int p = 0; p < 8; ++p) {
    const int e = (qraw[p * 64 + lane] >> 7) & 0xFF;
    c += (e >= 100 && e <= 141);
  }
  for (int off = 32; off; off >>= 1) c += __shfl_xor(c, off);
  return c < 300;  // bf16 data ~all in-range; f32 mantissa halves ~16%
}
__device__ __forceinline__ int det_i64(const int* iraw, int lane) {
  int nz = (lane < 16) ? (iraw[(lane + 1) * 32 + 1] != 0) : 0;
  return __ballot(nz) == 0ull;  // int64 -> odd words are zero high-halves
}

// ---------------------------------------------------------------------------
// prep: z=0..3 weight transpose (+bf16 canonicalize); z=4..6 bulk f32->bf16
// conversion of Q,K,V (conv blocks exit if inputs are bf16).
// ---------------------------------------------------------------------------
__global__ __launch_bounds__(256) void prep(
    const void* Q, const void* K, const void* V,
    const void* W0, const void* W1, const void* W2, const void* W3,
    u16* d0, u16* d1, u16* d2, u16* d3,
    u16* Qb, u16* Kb, u16* Vb) {
  const int tx = threadIdx.x, ty = threadIdx.y;
  const int t = ty * 32 + tx;
  const int f32 = det_f32((const u32*)Q, t & 63);
  const int z = blockIdx.z;
  if (z >= 4) {
    if (!f32) return;
    const void* s; u16* d;
    switch (z - 4) {
      case 0: s = Q; d = Qb; break;
      case 1: s = K; d = Kb; break;
      default: s = V; d = Vb; break;
    }
    const size_t i = ((size_t)(blockIdx.y * 32 + blockIdx.x) * 256 + t) * 16;
    *(u16x8*)(d + i) = ld8(s, i, 1);
    *(u16x8*)(d + i + 8) = ld8(s, i + 8, 1);
    return;
  }
  const void* src; u16* dst;
  switch (z) {
    case 0: src = W0; dst = d0; break;
    case 1: src = W1; dst = d1; break;
    case 2: src = W2; dst = d2; break;
    default: src = W3; dst = d3; break;
  }
  __shared__ u16 tile[32][33];
  const int bx = blockIdx.x * 32, by = blockIdx.y * 32;
#pragma unroll
  for (int i = 0; i < 4; ++i) {
    const int off = (by + ty + i * 8) * 1024 + bx + tx;
    tile[ty + i * 8][tx] = f32 ? f2b(((const float*)src)[off]) : ((const u16*)src)[off];
  }
  __syncthreads();
#pragma unroll
  for (int i = 0; i < 4; ++i)
    dst[(bx + ty + i * 8) * 1024 + by + tx] = tile[tx][ty + i * 8];
}

// ---------------------------------------------------------------------------
// GEMM: C[4096][1024] = A @ B with Bt N-major bf16. BM x 128 tile,
// dual-panel BK=64 (two stride-32 BK=32 panels per barrier -> 16 barriers,
// 32 MFMA/wave per barrier), global_load_lds staging, 4 waves (2x2).
// XCD swizzle: blockIdx.x = M-block (fastest) -> XCD = m%8 owns its A-strips.
// LDS: BM=128 -> 32 KB (3 blocks/CU with z-fused grid), BM=64 -> 24 KB.
// ---------------------------------------------------------------------------
template <int BM>
__device__ __forceinline__ void gemm_fast(const void* A, int a_f32,
                                          const u16* __restrict__ Bt,
                                          void* C, int c_f32) {
  constexpr int AI = BM / 64;  // A gl_lds16 per wave per panel
  __shared__ __align__(16) u16 As[2][BM * 32];
  __shared__ __align__(16) u16 Bs[2][128 * 32];
  const int t = threadIdx.x;
  const int lane = t & 63, w = t >> 6;
  const int bm = blockIdx.x * BM, bn = blockIdx.y * 128;
  const int lr = lane >> 2, lc = (lane & 3) * 8;
  const int wr = (w >> 1) * (BM / 2);
  const int wc = (w & 1) * 64;
  const int m16 = lane & 15, q4 = lane >> 4;
  f32x4 acc[BM / 32][4] = {};

  for (int k0 = 0; k0 < 1024; k0 += 64) {
#pragma unroll
    for (int ks = 0; ks < 2; ++ks) {
      const int kk = k0 + ks * 32;
      if (!a_f32) {
#pragma unroll
        for (int i = 0; i < AI; ++i)
          gl_lds16((const u16*)A + (size_t)(bm + w * 16 * AI + i * 16 + lr) * 1024 + kk + lc,
                   &As[ks][(w * 16 * AI + i * 16) * 32], lane);
      } else {
#pragma unroll
        for (int i = 0; i < AI; ++i)
          *(u16x8*)&As[ks][(w * 16 * AI + i * 16 + lr) * 32 + lc] =
              ld8(A, (size_t)(bm + w * 16 * AI + i * 16 + lr) * 1024 + kk + lc, 1);
      }
      gl_lds16(Bt + (size_t)(bn + w * 32 + lr) * 1024 + kk + lc,
               &Bs[ks][(w * 32) * 32], lane);
      gl_lds16(Bt + (size_t)(bn + w * 32 + 16 + lr) * 1024 + kk + lc,
               &Bs[ks][(w * 32 + 16) * 32], lane);
    }
    __syncthreads();
#pragma unroll
    for (int ks = 0; ks < 2; ++ks) {
      bf16x8_t af[BM / 32], bfr[4];
#pragma unroll
      for (int i = 0; i < BM / 32; ++i)
        af[i] = *(const bf16x8_t*)&As[ks][(wr + i * 16 + m16) * 32 + q4 * 8];
#pragma unroll
      for (int j = 0; j < 4; ++j)
        bfr[j] = *(const bf16x8_t*)&Bs[ks][(wc + j * 16 + m16) * 32 + q4 * 8];
#pragma unroll
      for (int i = 0; i < BM / 32; ++i)
#pragma unroll
        for (int j = 0; j < 4; ++j)
          acc[i][j] = __builtin_amdgcn_mfma_f32_16x16x32_bf16(af[i], bfr[j], acc[i][j], 0, 0, 0);
    }
    __syncthreads();
  }
  // C/D layout: col = lane&15, row = (lane>>4)*4 + reg (m89/m91).
#pragma unroll
  for (int i = 0; i < BM / 32; ++i)
#pragma unroll
    for (int r = 0; r < 4; ++r) {
      const int row = bm + wr + i * 16 + q4 * 4 + r;
#pragma unroll
      for (int j = 0; j < 4; ++j) {
        const int col = bn + wc + j * 16 + m16;
        const float x = acc[i][j][r];
        if (c_f32) ((float*)C)[(size_t)row * 1024 + col] = x;
        else       ((u16*)C)[(size_t)row * 1024 + col] = f2b(x);
      }
    }
}

__global__ __launch_bounds__(256) void gemm_qkv(
    const void* Q, const void* K, const void* V,
    const u16* Qb, const u16* Kb, const u16* Vb,
    const u16* WqT, const u16* WkT, const u16* WvT,
    u16* q, u16* k, u16* v, int big) {
  const int f32 = det_f32((const u32*)Q, threadIdx.x & 63);
  const void* Araw; const u16* Ab; const u16* Bt; u16* Cp;
  switch (blockIdx.z) {
    case 0:  Araw = Q; Ab = Qb; Bt = WqT; Cp = q; break;
    case 1:  Araw = K; Ab = Kb; Bt = WkT; Cp = k; break;
    default: Araw = V; Ab = Vb; Bt = WvT; Cp = v; break;
  }
  if (big && f32) gemm_fast<128>(Ab, 0, Bt, Cp, 0);
  else            gemm_fast<128>(Araw, f32, Bt, Cp, 0);
}

__global__ __launch_bounds__(256) void gemm_out(
    const void* Qdet, const u16* A, const u16* WoT, void* C) {
  const int f32 = det_f32((const u32*)Qdet, threadIdx.x & 63);
  gemm_fast<64>(A, 0, WoT, C, f32);
}

// ---------------------------------------------------------------------------
// attn: fully wave-autonomous, zero LDS / zero barriers.
// blocks 0..255   : global-token partials, 1 wave = (q,h,chunk-of-128-keys).
// blocks 256..4349: selected attention, 1 wave = 4 heads of one query;
//                   row indices/offsets hoisted once, reused logits+PV.
// ---------------------------------------------------------------------------
__global__ __launch_bounds__(256) void attn(
    u16* qp, const u16* __restrict__ kp, const u16* __restrict__ vp,
    const int* __restrict__ idx, float* __restrict__ part) {
  const int t = threadIdx.x;
  const int w = t >> 6, lane = t & 63;
  const int jj = lane >> 3, dl = lane & 7;

  if (blockIdx.x < 256) {
    // ---- global-token partials: wave gw = (qi, h, c), keys c*128..+128 ----
    const int gw = blockIdx.x * 4 + w;
    const int qi = gw >> 9, h = (gw >> 5) & 15, c = gw & 31;
    const int s = qi ? 4095 : 0;
    f32x2 qreg[4];
    {
      const u32x4 qw = *(const u32x4*)(qp + (size_t)s * 1024 + h * 64 + dl * 8);
#pragma unroll
      for (int cc = 0; cc < 4; ++cc) qreg[cc] = up2(qw[cc]);
    }
    float lre[16];
#pragma unroll
    for (int p = 0; p < 16; ++p) {
      const int n = c * 128 + p * 8 + jj;
      const u32x4 kw = *(const u32x4*)(kp + (size_t)n * 1024 + h * 64 + dl * 8);
      f32x2 a2 = {0.f, 0.f};
#pragma unroll
      for (int cc = 0; cc < 4; ++cc)
        a2 = __builtin_elementwise_fma(up2(kw[cc]), qreg[cc], a2);
      float acc = a2[0] + a2[1];
      acc += __shfl_xor(acc, 1);
      acc += __shfl_xor(acc, 2);
      acc += __shfl_xor(acc, 4);
      lre[p] = acc * 0.125f;
    }
    float mx = lre[0];
#pragma unroll
    for (int p = 1; p < 16; ++p) mx = fmaxf(mx, lre[p]);
    mx = fmaxf(mx, __shfl_xor(mx, 8));
    mx = fmaxf(mx, __shfl_xor(mx, 16));
    mx = fmaxf(mx, __shfl_xor(mx, 32));
    float sm = 0.f;
#pragma unroll
    for (int p = 0; p < 16; ++p) { lre[p] = __expf(lre[p] - mx); sm += lre[p]; }
    sm += __shfl_xor(sm, 8);
    sm += __shfl_xor(sm, 16);
    sm += __shfl_xor(sm, 32);
    f32x2 acc2[4] = {};
#pragma unroll
    for (int p = 0; p < 16; ++p) {
      const int n = c * 128 + p * 8 + jj;
      const u32x4 vw = *(const u32x4*)(vp + (size_t)n * 1024 + h * 64 + dl * 8);
      const f32x2 pp = {lre[p], lre[p]};
#pragma unroll
      for (int cc = 0; cc < 4; ++cc)
        acc2[cc] = __builtin_elementwise_fma(up2(vw[cc]), pp, acc2[cc]);
    }
#pragma unroll
    for (int cc = 0; cc < 4; ++cc)
#pragma unroll
      for (int e = 0; e < 2; ++e) {
        acc2[cc][e] += __shfl_xor(acc2[cc][e], 8);
        acc2[cc][e] += __shfl_xor(acc2[cc][e], 16);
        acc2[cc][e] += __shfl_xor(acc2[cc][e], 32);
      }
    float* dst = part + ((size_t)((qi * 16 + h) * 32 + c)) * 72;
    if (lane == 0) { dst[0] = mx; dst[1] = sm; }
    if (jj == 0) {
#pragma unroll
      for (int cc = 0; cc < 4; ++cc) {
        dst[8 + dl * 8 + cc * 2] = acc2[cc][0];
        dst[8 + dl * 8 + cc * 2 + 1] = acc2[cc][1];
      }
    }
    return;
  }

  // ---- selected attention: wave w owns heads w*4..w*4+3 of query s ----
  const int b = blockIdx.x - 256;
  int s0 = (b & 7) * 512 + (b >> 3);
  if (s0 >= 4094) s0 = 3583;  // bijective remap (source b=4094 doesn't exist)
  const int s = s0 + 1;
  const int i64f = det_i64(idx, lane);
  int myidx;
  {
    const size_t e = (size_t)(s - 1) * 32 + (lane & 31);
    myidx = i64f ? idx[2 * e] : idx[e];
  }
  // Hoist the 4 row offsets this lane uses (q*8+jj), shared by logits and PV.
  size_t rowoff[4];
#pragma unroll
  for (int q = 0; q < 4; ++q)
    rowoff[q] = (size_t)__shfl(myidx, q * 8 + jj) * 1024 + dl * 8;

  const int h0 = w * 4;
  f32x2 qreg[4][4];
#pragma unroll
  for (int hh = 0; hh < 4; ++hh) {
    const u32x4 qw = *(const u32x4*)(qp + (size_t)s * 1024 + (h0 + hh) * 64 + dl * 8);
#pragma unroll
    for (int cc = 0; cc < 4; ++cc) qreg[hh][cc] = up2(qw[cc]);
  }

  // logits -> lre[hh][q], value for j = q*8+jj held by the lanes that use it.
  float lre[4][4];
#pragma unroll
  for (int p = 0; p < 16; ++p) {
    const int hh = p >> 2, q = p & 3;
    const u32x4 kw = *(const u32x4*)(kp + rowoff[q] + (h0 + hh) * 64);
    f32x2 a2 = {0.f, 0.f};
#pragma unroll
    for (int cc = 0; cc < 4; ++cc)
      a2 = __builtin_elementwise_fma(up2(kw[cc]), qreg[hh][cc], a2);
    float acc = a2[0] + a2[1];
    acc += __shfl_xor(acc, 1);
    acc += __shfl_xor(acc, 2);
    acc += __shfl_xor(acc, 4);
    lre[hh][q] = acc * 0.125f;
  }

  // softmax per head, in-register + jj-shuffles (dl lanes hold duplicates).
#pragma unroll
  for (int hh = 0; hh < 4; ++hh) {
    float mx = fmaxf(fmaxf(lre[hh][0], lre[hh][1]), fmaxf(lre[hh][2], lre[hh][3]));
    mx = fmaxf(mx, __shfl_xor(mx, 8));
    mx = fmaxf(mx, __shfl_xor(mx, 16));
    mx = fmaxf(mx, __shfl_xor(mx, 32));
    float sm = 0.f;
#pragma unroll
    for (int q = 0; q < 4; ++q) { lre[hh][q] = __expf(lre[hh][q] - mx); sm += lre[hh][q]; }
    sm += __shfl_xor(sm, 8);
    sm += __shfl_xor(sm, 16);
    sm += __shfl_xor(sm, 32);
    const float r = 1.f / sm;
#pragma unroll
    for (int q = 0; q < 4; ++q) lre[hh][q] *= r;
  }

  // PV per head: gather v rows at the hoisted offsets, weight, jj-reduce.
#pragma unroll
  for (int hh = 0; hh < 4; ++hh) {
    f32x2 acc2[4] = {};
#pragma unroll
    for (int q = 0; q < 4; ++q) {
      const u32x4 vw = *(const u32x4*)(vp + rowoff[q] + (h0 + hh) * 64);
      const f32x2 pp = {lre[hh][q], lre[hh][q]};
#pragma unroll
      for (int cc = 0; cc < 4; ++cc)
        acc2[cc] = __builtin_elementwise_fma(up2(vw[cc]), pp, acc2[cc]);
    }
#pragma unroll
    for (int cc = 0; cc < 4; ++cc)
#pragma unroll
      for (int e = 0; e < 2; ++e) {
        acc2[cc][e] += __shfl_xor(acc2[cc][e], 8);
        acc2[cc][e] += __shfl_xor(acc2[cc][e], 16);
        acc2[cc][e] += __shfl_xor(acc2[cc][e], 32);
      }
    if (jj == 0) {
      u16x8 o;
#pragma unroll
      for (int cc = 0; cc < 4; ++cc) {
        o[cc * 2] = f2b(acc2[cc][0]);
        o[cc * 2 + 1] = f2b(acc2[cc][1]);
      }
      *(u16x8*)(qp + (size_t)s * 1024 + (h0 + hh) * 64 + dl * 8) = o;
    }
  }
}

// Combine 32 global-token partials per (q, head).
__global__ void attn_glb_b(u16* __restrict__ qp, const float* __restrict__ part) {
  const int qi = blockIdx.x >> 4, h = blockIdx.x & 15;
  const int s = qi ? 4095 : 0;
  const int t = threadIdx.x;  // 64
  const float* p = part + ((size_t)((qi * 16 + h) * 32)) * 72;
  float gm = -1e30f;
#pragma unroll
  for (int c = 0; c < 32; ++c) gm = fmaxf(gm, p[c * 72]);
  float S = 0.f, o = 0.f;
#pragma unroll
  for (int c = 0; c < 32; ++c) {
    const float w = __expf(p[c * 72] - gm);
    S += p[c * 72 + 1] * w;
    o += p[c * 72 + 8 + t] * w;
  }
  qp[(size_t)s * 1024 + h * 64 + t] = f2b(o / S);
}

// ---------------------------------------------------------------------------
extern "C" void kernel_launch(void* const* d_in, const int* in_sizes, int n_in,
                              void* d_out, int out_size, void* d_ws, size_t ws_size,
                              hipStream_t stream) {
  const void* Q  = d_in[0];
  const void* K  = d_in[1];
  const void* V  = d_in[2];
  const void* Wq = d_in[3];
  const void* Wk = d_in[4];
  const void* Wv = d_in[5];
  const void* Wo = d_in[6];
  const int* idx = (const int*)d_in[7];

  // workspace: 24 MB guaranteed; +4 KB pad + 24 MB conv buffers if ws allows.
  u16* WqT = (u16*)d_ws;
  u16* WkT = WqT + (1 << 20);
  u16* WvT = WkT + (1 << 20);
  u16* WoT = WvT + (1 << 20);
  u16* qp  = WoT + (1 << 20);          // q proj, later full attention output
  u16* vp  = qp + (4 << 20);
  float* part = (float*)WkT;           // overlay: WkT dead after QKV GEMMs
  u16* kp = (u16*)d_out;               // k proj scratch inside d_out
  u16* Qb = (u16*)((char*)d_ws + (24ull << 20) + 4096);
  u16* Kb = Qb + (4 << 20);
  u16* Vb = Kb + (4 << 20);
  const bool big = ws_size >= (48ull << 20) + 8192;

  prep<<<dim3(32, 32, big ? 7 : 4), dim3(32, 8), 0, stream>>>(
      Q, K, V, Wq, Wk, Wv, Wo, WqT, WkT, WvT, WoT, Qb, Kb, Vb);
  gemm_qkv<<<dim3(32, 8, 3), 256, 0, stream>>>(
      Q, K, V, Qb, Kb, Vb, WqT, WkT, WvT, qp, kp, vp, big ? 1 : 0);
  attn<<<4350, 256, 0, stream>>>(qp, kp, vp, idx, part);
  attn_glb_b<<<32, 64, 0, stream>>>(qp, part);
  gemm_out<<<dim3(64, 8), 256, 0, stream>>>(Q, qp, WoT, d_out);
}